// Round 4
// baseline (476.110 us; speedup 1.0000x reference)
//
#include <hip/hip_runtime.h>
#include <hip/hip_bf16.h>

// Problem constants (fixed by reference setup_inputs).
#define T_TOTAL 2048
#define BATCH   128
#define NIN     256
#define NOUT    128

// Reverse-scan formulation:
//   rtrace[t] = out[t] + 0.5*rtrace[t+1]   (reverse scan over out-spikes)
//   dw[o,i]  = sum_{t,b} rtrace[t,b,o] * in[t,b,i]
// The recurrence lives on the NOUT side; `in` feeds MFMA raw (binary -> bf16
// conversion is exact). For mfma_f32_32x32x16_bf16, lane (l31, kh) of a wave
// needs A[k]=rtrace only for b in {2kh, 2kh+1} -> each lane scans its own two
// (o,b) traces IN REGISTERS. Zero cross-lane traffic => NO LDS, NO BARRIERS.
//
// ROUND 4 CHANGE (epilogue + launch path only; main loop byte-identical to R3):
// never touch d_ws. The harness re-poisons the 1 GiB workspace every iteration
// (~2 x 160 us fillBufferAligned = ~320 us of the ~453 us total). Hypothesis:
// avoiding d_ws entirely removes that cost from the timed region. Sum of the
// 256 per-block partials is done with fp32 device atomics into d_out instead
// (8.4M atomics, ~+20-40 us premium), after a cheap 128 KB zero of d_out.
#define TC      256                 // timesteps per block
#define BC      4                   // batches per block
#define WARM    32                  // reverse warm-up steps (0.5^32 ~ 2e-10)
#define G       4                   // timesteps per MFMA K-group (K = G*BC = 16)
#define NTC     (T_TOTAL / TC)      // 8
#define NBC     (BATCH / BC)        // 32
#define NBLOCKS (NTC * NBC)         // 256  (1 block/CU)
#define NG      (TC / G)            // 64 K-groups per block

#define OUT_ELEMS (NOUT * NIN)      // 32768

static_assert(NG % 2 == 0, "2-stage pipeline needs even group count");

typedef __attribute__((ext_vector_type(8)))  __bf16 bf16x8;
typedef __attribute__((ext_vector_type(2)))  __bf16 bf16x2;
typedef __attribute__((ext_vector_type(16))) float  f32x16;

// packed f32x2 -> bf16x2 (v_cvt_pk_bf16_f32 on gfx950, RTNE; exact for {0,1})
static __device__ __forceinline__ unsigned pack_bf16(float a, float b) {
    bf16x2 v = { (__bf16)a, (__bf16)b };
    union { bf16x2 v; unsigned u; } c; c.v = v; return c.u;
}

static __device__ __forceinline__ bf16x8 frag_from4(unsigned d0, unsigned d1,
                                                    unsigned d2, unsigned d3) {
    union { unsigned u[4]; bf16x8 v; } c;
    c.u[0] = d0; c.u[1] = d1; c.u[2] = d2; c.u[3] = d3; return c.v;
}

// Wave w = (mt = w&3, nh = w>>2): output tile o in [mt*32, mt*32+32),
// i in [nh*128, nh*128+128). Lane (l31 = lane&31, kh = lane>>5):
//   A-frag element j (k = kh*8+j): b_local = 2kh + (j>=4), q = j&3
//     -> lane scans rtrace for (o = mt*32+l31, b = b0+2kh) and (o, b0+2kh+1).
//   B-frag element j for tile tn:  in[t0+4g+(j&3), b0+2kh+(j>=4), (nh*4+tn)*32+l31]
//     -> direct global loads, 128B-coalesced across l31.
// 2-deep register prefetch per wave; no __syncthreads anywhere.
__global__ __launch_bounds__(512, 2)
void stdp_main(const float* __restrict__ in, const float* __restrict__ outs,
               float* __restrict__ dst)
{
    const int tid = threadIdx.x;
    const int bc  = blockIdx.x % NBC;
    const int tc  = blockIdx.x / NBC;
    const int b0  = bc * BC;
    const int t0  = tc * TC;

    const int lane = tid & 63;
    const int wv   = tid >> 6;           // 8 waves, fully independent
    const int mt   = wv & 3;             // o-tile (rows mt*32..+31)
    const int nh   = wv >> 2;            // i-half (cols nh*128..+127)
    const int l31  = lane & 31;
    const int kh   = lane >> 5;          // selects b-pair {2kh, 2kh+1}

    const size_t IST = (size_t)BATCH * NIN;    // floats per timestep in `in`
    const size_t OST = (size_t)BATCH * NOUT;

    const float* __restrict__ inW  = in   + (size_t)(b0 + 2 * kh) * NIN  + nh * 128 + l31;
    const float* __restrict__ outW = outs + (size_t)(b0 + 2 * kh) * NOUT + mt * 32  + l31;

    float rtrA = 0.f, rtrB = 0.f;        // reverse traces for b0+2kh, b0+2kh+1

    // ---- reverse warm-up over the WARM timesteps after this chunk ----
    if (tc < NTC - 1) {
        for (int tb = t0 + TC + WARM; tb > t0 + TC; tb -= 8) {
            float vA[8], vB[8];
#pragma unroll
            for (int u = 0; u < 8; ++u) {
                vA[u] = outW[(size_t)(tb - 1 - u) * OST];
                vB[u] = outW[(size_t)(tb - 1 - u) * OST + NOUT];
            }
#pragma unroll
            for (int u = 0; u < 8; ++u) {
                rtrA = vA[u] + 0.5f * rtrA;
                rtrB = vB[u] + 0.5f * rtrB;
            }
        }
    }

    f32x16 acc[4];
#pragma unroll
    for (int j = 0; j < 4; ++j) acc[j] = (f32x16)(0.f);

    // 2-stage register prefetch: A-side (out) 8 floats, B-side (in) 32 floats.
    float AO[2][8];
    float BI[2][32];

    auto load_stage = [&](int s, int g) {
        const int tg = t0 + g * G;
        // A first: feeds the serial scan at the top of body().
#pragma unroll
        for (int q = 0; q < G; ++q) {
            AO[s][q]     = outW[(size_t)(tg + q) * OST];
            AO[s][4 + q] = outW[(size_t)(tg + q) * OST + NOUT];
        }
#pragma unroll
        for (int tn = 0; tn < 4; ++tn)
#pragma unroll
            for (int be = 0; be < 2; ++be)
#pragma unroll
                for (int q = 0; q < G; ++q)
                    BI[s][tn * 8 + be * 4 + q] =
                        inW[(size_t)(tg + q) * IST + be * NIN + tn * 32];
    };

    auto body = [&](int s, int g) {
        // reverse scan over this group's 4 timesteps (descending t)
        float aA[4], aB[4];
#pragma unroll
        for (int q = 3; q >= 0; --q) {
            rtrA = AO[s][q]     + 0.5f * rtrA; aA[q] = rtrA;
            rtrB = AO[s][4 + q] + 0.5f * rtrB; aB[q] = rtrB;
        }
        const bf16x8 a = frag_from4(pack_bf16(aA[0], aA[1]), pack_bf16(aA[2], aA[3]),
                                    pack_bf16(aB[0], aB[1]), pack_bf16(aB[2], aB[3]));
        bf16x8 bfr[4];
#pragma unroll
        for (int tn = 0; tn < 4; ++tn) {
            const float* p = &BI[s][tn * 8];
            bfr[tn] = frag_from4(pack_bf16(p[0], p[1]), pack_bf16(p[2], p[3]),
                                 pack_bf16(p[4], p[5]), pack_bf16(p[6], p[7]));
        }
        // stage s registers free: issue loads for group g-2 (reverse order)
        if (g >= 2) load_stage(s, g - 2);
#pragma unroll
        for (int tn = 0; tn < 4; ++tn)
            acc[tn] = __builtin_amdgcn_mfma_f32_32x32x16_bf16(a, bfr[tn], acc[tn], 0, 0, 0);
    };

    load_stage(1, NG - 1);
    load_stage(0, NG - 2);
    for (int gg = NG - 1; gg >= 1; gg -= 2) {
        body(1, gg);
        body(0, gg - 1);
    }

    // ---- epilogue: atomic accumulation straight into d_out ----
    // D[row, col] -> dw[o = mt*32+row, i = (nh*4+j)*32+col].
    // Per-block rotation of the (j, r) visit order de-lockstops the 256 blocks
    // that all write the same 32768 addresses.
    const int jrot = blockIdx.x & 3;
    const int rrot = (blockIdx.x >> 2) & 15;
#pragma unroll
    for (int jj = 0; jj < 4; ++jj) {
        const int j    = (jj + jrot) & 3;
        const int icol = (nh * 4 + j) * 32 + l31;
#pragma unroll
        for (int rr = 0; rr < 16; ++rr) {
            const int r   = (rr + rrot) & 15;
            const int row = (r & 3) + 8 * (r >> 2) + 4 * kh;
            const int o   = mt * 32 + row;
            atomicAdd(&dst[o * NIN + icol], acc[j][r]);
        }
    }
}

__global__ void zero_kernel(float* p, int n) {
    int i = blockIdx.x * blockDim.x + threadIdx.x;
    if (i < n) p[i] = 0.f;
}

extern "C" void kernel_launch(void* const* d_in, const int* in_sizes, int n_in,
                              void* d_out, int out_size, void* d_ws, size_t ws_size,
                              hipStream_t stream) {
    const float* in   = (const float*)d_in[0];
    const float* outs = (const float*)d_in[1];
    float* out = (float*)d_out;

    // Deliberately ignore d_ws: the harness re-poisons the whole 1 GiB
    // workspace each iteration (~320 us of fillBufferAligned). Zero the
    // 128 KB output and accumulate partials with device atomics instead.
    zero_kernel<<<(OUT_ELEMS + 255) / 256, 256, 0, stream>>>(out, OUT_ELEMS);
    stdp_main<<<NBLOCKS, 512, 0, stream>>>(in, outs, out);
}

// Round 5
// 442.753 us; speedup vs baseline: 1.0753x; 1.0753x over previous
//
#include <hip/hip_runtime.h>
#include <hip/hip_bf16.h>

// Problem constants (fixed by reference setup_inputs).
#define T_TOTAL 2048
#define BATCH   128
#define NIN     256
#define NOUT    128

// Reverse-scan formulation (see R3):
//   rtrace[t] = out[t] + 0.5*rtrace[t+1];  dw[o,i] = sum_{t,b} rtrace[t,b,o]*in[t,b,i]
//
// ROUND 5 CHANGE — DRAM-granularity attack. All previous variants (1.8-2.15
// TB/s) loaded 256-512 B granules scattered at 64-128 KiB strides; that
// pattern caps HBM efficiency at ~25%. For fixed t the block's 4 batches are
// ADJACENT in memory: in[t][b0..b0+4][:] = 4 KiB contiguous, out = 2 KiB.
// So stage whole rows via global_load_lds width=16 (direct HBM->LDS DMA,
// linear dest = wave base + lane*16): per group the block emits a perfectly
// sequential 16 KiB + 8 KiB address stream. Fragments are rebuilt from LDS
// with ds_read_b32 (+cvt_pk); all LDS offsets fold into 16-bit immediates;
// worst aliasing is 2 lanes/bank (free). Sync = counted-vmcnt (T4): vmcnt(3)
// + barrier before consume, lgkmcnt(0) + barrier before stage reuse, 2-deep
// double buffer; vmcnt never drains to 0 in steady state.
#define TC      256                 // timesteps per block
#define BC      4                   // batches per block
#define WARM    32                  // reverse warm-up steps (0.5^32 ~ 2e-10)
#define G       4                   // timesteps per MFMA K-group (K = G*BC = 16)
#define NTC     (T_TOTAL / TC)      // 8
#define NBC     (BATCH / BC)        // 32
#define NBLOCKS (NTC * NBC)         // 256  (1 block/CU)
#define NG      (TC / G)            // 64 K-groups per block

#define OUT_ELEMS (NOUT * NIN)      // 32768

static_assert(NG % 2 == 0, "2-stage pipeline needs even group count");

typedef __attribute__((ext_vector_type(8)))  __bf16 bf16x8;
typedef __attribute__((ext_vector_type(2)))  __bf16 bf16x2;
typedef __attribute__((ext_vector_type(16))) float  f32x16;

// packed f32x2 -> bf16x2 (v_cvt_pk_bf16_f32 on gfx950, RTNE; exact for {0,1})
static __device__ __forceinline__ unsigned pack_bf16(float a, float b) {
    bf16x2 v = { (__bf16)a, (__bf16)b };
    union { bf16x2 v; unsigned u; } c; c.v = v; return c.u;
}

static __device__ __forceinline__ bf16x8 frag_from4(unsigned d0, unsigned d1,
                                                    unsigned d2, unsigned d3) {
    union { unsigned u[4]; bf16x8 v; } c;
    c.u[0] = d0; c.u[1] = d1; c.u[2] = d2; c.u[3] = d3; return c.v;
}

// Direct global->LDS DMA, 16 B/lane. LDS dest = wave-uniform base + lane*16
// (m104); size must be a literal.
static __device__ __forceinline__ void gload16(const float* g, void* l) {
    __builtin_amdgcn_global_load_lds(
        (const __attribute__((address_space(1))) void*)g,
        (__attribute__((address_space(3))) void*)l,
        16, 0, 0);
}

// Wave w = (mt = w&3, nh = w>>2): output tile o in [mt*32,+32), i in
// [nh*128,+128). Lane (l31, kh): A-frag elem j: (q=j&3, b=2kh+(j>=4)) ->
// lane scans rtrace for (o=mt*32+l31, b0+2kh / b0+2kh+1) in registers.
// B-frag elem j, tile tn: in[tg+(j&3)][b0+2kh+(j>=4)][(nh*4+tn)*32+l31].
__global__ __launch_bounds__(512, 2)
void stdp_main(const float* __restrict__ in, const float* __restrict__ outs,
               float* __restrict__ dst, int nslots, int use_atomic)
{
    // fp32 staging, layout == global layout (linear, required by DMA):
    // in_lds [s][q(4)][b(4)][i(256)]  = 16 KiB/stage
    // out_lds[s][q(4)][b(4)][o(128)]  =  8 KiB/stage
    __shared__ float in_lds [2][G * BC * NIN];
    __shared__ float out_lds[2][G * BC * NOUT];

    const int tid = threadIdx.x;
    const int bc  = blockIdx.x % NBC;
    const int tc  = blockIdx.x / NBC;
    const int b0  = bc * BC;
    const int t0  = tc * TC;

    const int lane = tid & 63;
    const int wv   = tid >> 6;           // 8 waves
    const int mt   = wv & 3;             // o-tile (rows mt*32..+31)
    const int nh   = wv >> 2;            // i-half (cols nh*128..+127)
    const int l31  = lane & 31;
    const int kh   = lane >> 5;          // selects b-pair {2kh, 2kh+1}

    const size_t OST = (size_t)BATCH * NOUT;

    // ---- reverse warm-up (scalar loads; 16 MB total chip-wide, ~3% of traffic)
    const float* __restrict__ outW = outs + (size_t)(b0 + 2 * kh) * NOUT + mt * 32 + l31;
    float rtrA = 0.f, rtrB = 0.f;
    if (tc < NTC - 1) {
        for (int tb = t0 + TC + WARM; tb > t0 + TC; tb -= 8) {
            float vA[8], vB[8];
#pragma unroll
            for (int u = 0; u < 8; ++u) {
                vA[u] = outW[(size_t)(tb - 1 - u) * OST];
                vB[u] = outW[(size_t)(tb - 1 - u) * OST + NOUT];
            }
#pragma unroll
            for (int u = 0; u < 8; ++u) {
                rtrA = vA[u] + 0.5f * rtrA;
                rtrB = vB[u] + 0.5f * rtrB;
            }
        }
    }

    f32x16 acc[4];
#pragma unroll
    for (int j = 0; j < 4; ++j) acc[j] = (f32x16)(0.f);

    // ---- DMA decomposition (derived so LDS-linear == global-contiguous):
    // in chunk 16 KiB = 16 x (t,b)-rows of 1 KiB; wave wv, instr r covers
    //   (q = 2r + (wv>>2), b = wv&3), lanes span i = lane*4..+3.
    // out chunk 8 KiB = 8 pieces; wave wv covers (q = wv>>1,
    //   b = 2*(wv&1) + (lane>>5)), lanes span o = (lane&31)*4..+3.
    const float* inS  = in   + (size_t)(b0 + (wv & 3)) * NIN  + lane * 4;
    const float* outS = outs + (size_t)(b0 + 2 * (wv & 1) + kh) * NOUT + l31 * 4;
    const int    tin  = wv >> 2;         // + 2r
    const int    tot  = wv >> 1;
    char* inL  = (char*)&in_lds[0][0]  + wv * 1024;
    char* outL = (char*)&out_lds[0][0] + wv * 1024;

    auto dma_group = [&](int s, int g) {    // 3 DMA instrs / thread / group
        const int tg = t0 + g * G;
        gload16(inS  + (size_t)(tg + tin)     * (BATCH * NIN),  inL + s * 16384);
        gload16(inS  + (size_t)(tg + tin + 2) * (BATCH * NIN),  inL + s * 16384 + 8192);
        gload16(outS + (size_t)(tg + tot)     * (BATCH * NOUT), outL + s * 8192);
    };

    // LDS frag-read bases (byte offsets; q/be/tn/s fold into ds imm offsets).
    // B: byte = s*16384 + q*4096 + be*1024 + [kh*2048 + nh*512 + tn*128 + l31*4]
    // A: byte = s*8192  + q*2048 + be*512  + [kh*1024 + mt*128 + l31*4]
    const char* ilb = (const char*)&in_lds [0][0] + kh * 2048 + nh * 512 + l31 * 4;
    const char* olb = (const char*)&out_lds[0][0] + kh * 1024 + mt * 128 + l31 * 4;

    auto body = [&](int s, int g, int vm) {
        // stage-s DMAs are the 3 oldest outstanding; 3 newer may stay in flight
        if (vm) asm volatile("s_waitcnt vmcnt(3)" ::: "memory");
        else    asm volatile("s_waitcnt vmcnt(0)" ::: "memory");
        __builtin_amdgcn_s_barrier();            // all waves' stage-s data landed
        __builtin_amdgcn_sched_barrier(0);       // no ds_read hoists above

        // A side: read out-spike rows, reverse-scan rtrace (descending t)
        float vA[4], vB[4];
#pragma unroll
        for (int q = 0; q < 4; ++q) {
            vA[q] = *(const float*)(olb + s * 8192 + q * 2048);        // b = 2kh
            vB[q] = *(const float*)(olb + s * 8192 + q * 2048 + 512);  // b = 2kh+1
        }
        float aA[4], aB[4];
#pragma unroll
        for (int q = 3; q >= 0; --q) {
            rtrA = vA[q] + 0.5f * rtrA; aA[q] = rtrA;
            rtrB = vB[q] + 0.5f * rtrB; aB[q] = rtrB;
        }
        const bf16x8 a = frag_from4(pack_bf16(aA[0], aA[1]), pack_bf16(aA[2], aA[3]),
                                    pack_bf16(aB[0], aB[1]), pack_bf16(aB[2], aB[3]));
        bf16x8 bfr[4];
#pragma unroll
        for (int tn = 0; tn < 4; ++tn) {
            float p[8];
#pragma unroll
            for (int be = 0; be < 2; ++be)
#pragma unroll
                for (int q = 0; q < 4; ++q)
                    p[be * 4 + q] = *(const float*)
                        (ilb + s * 16384 + q * 4096 + be * 1024 + tn * 128);
            bfr[tn] = frag_from4(pack_bf16(p[0], p[1]), pack_bf16(p[2], p[3]),
                                 pack_bf16(p[4], p[5]), pack_bf16(p[6], p[7]));
        }
#pragma unroll
        for (int tn = 0; tn < 4; ++tn)
            acc[tn] = __builtin_amdgcn_mfma_f32_32x32x16_bf16(a, bfr[tn], acc[tn], 0, 0, 0);

        asm volatile("s_waitcnt lgkmcnt(0)" ::: "memory");  // my stage-s reads done
        __builtin_amdgcn_s_barrier();                       // everyone's reads done
        __builtin_amdgcn_sched_barrier(0);                  // DMA stays below barrier
        if (g >= 2) dma_group(s, g - 2);                    // refill stage s
    };

    // prologue: 6 DMAs outstanding, then steady-state 2-deep pipeline
    dma_group(1, NG - 1);
    dma_group(0, NG - 2);
    for (int gg = NG - 1; gg >= 3; gg -= 2) {
        body(1, gg, 1);
        body(0, gg - 1, 1);
    }
    body(1, 1, 1);
    body(0, 0, 0);   // last group: drain fully

    // ---- epilogue: D[row, col] -> dw[o = mt*32+row, i = (nh*4+j)*32+col] ----
    float* base = dst + (size_t)(use_atomic ? (blockIdx.x % nslots) : blockIdx.x) * OUT_ELEMS;
#pragma unroll
    for (int j = 0; j < 4; ++j) {
        const int icol = (nh * 4 + j) * 32 + l31;
#pragma unroll
        for (int r = 0; r < 16; ++r) {
            const int row = (r & 3) + 8 * (r >> 2) + 4 * kh;
            const int o   = mt * 32 + row;
            const float v = acc[j][r];
            if (use_atomic) atomicAdd(&base[o * NIN + icol], v);
            else            base[o * NIN + icol] = v;
        }
    }
}

__global__ void zero_kernel(float* p, int n) {
    int i = blockIdx.x * blockDim.x + threadIdx.x;
    if (i < n) p[i] = 0.f;
}

__global__ __launch_bounds__(256)
void reduce_kernel(const float* __restrict__ ws, float* __restrict__ outp, int nslots) {
    const int idx = blockIdx.x * 256 + threadIdx.x;
    float s = 0.f;
    int k = 0;
    for (; k + 16 <= nslots; k += 16) {
        float v[16];
#pragma unroll
        for (int u = 0; u < 16; ++u) v[u] = ws[(size_t)(k + u) * OUT_ELEMS + idx];
#pragma unroll
        for (int u = 0; u < 16; ++u) s += v[u];
    }
    for (; k < nslots; ++k) s += ws[(size_t)k * OUT_ELEMS + idx];
    outp[idx] = s;
}

extern "C" void kernel_launch(void* const* d_in, const int* in_sizes, int n_in,
                              void* d_out, int out_size, void* d_ws, size_t ws_size,
                              hipStream_t stream) {
    const float* in   = (const float*)d_in[0];
    const float* outs = (const float*)d_in[1];
    float* out = (float*)d_out;
    float* ws  = (float*)d_ws;

    const size_t slot_bytes = (size_t)OUT_ELEMS * sizeof(float);

    if (ws_size >= (size_t)NBLOCKS * slot_bytes) {
        // plain per-block partials + reduce (preferred; atomics cost ~+30 us, R4)
        stdp_main<<<NBLOCKS, 512, 0, stream>>>(in, outs, ws, NBLOCKS, 0);
        reduce_kernel<<<OUT_ELEMS / 256, 256, 0, stream>>>(ws, out, NBLOCKS);
    } else if (ws_size >= 16 * slot_bytes) {
        zero_kernel<<<(16 * OUT_ELEMS + 255) / 256, 256, 0, stream>>>(ws, 16 * OUT_ELEMS);
        stdp_main<<<NBLOCKS, 512, 0, stream>>>(in, outs, ws, 16, 1);
        reduce_kernel<<<OUT_ELEMS / 256, 256, 0, stream>>>(ws, out, 16);
    } else {
        zero_kernel<<<(OUT_ELEMS + 255) / 256, 256, 0, stream>>>(out, OUT_ELEMS);
        stdp_main<<<NBLOCKS, 512, 0, stream>>>(in, outs, out, 1, 1);
    }
}